// Round 14
// baseline (423.484 us; speedup 1.0000x reference)
//
#include <hip/hip_runtime.h>
#include <hip/hip_bf16.h>
#include <cstdint>
#include <cstddef>

#define TT 4096   // tokens
#define DM 1024   // d_model
#define DF 4096   // d_ffn
#define NE 8      // experts
#define BTAB 72   // max 128-row blocks over all experts
#define BTAB2 40  // max 256-row blocks over all experts

typedef __attribute__((ext_vector_type(8))) short bf16x8;
typedef __attribute__((ext_vector_type(8))) unsigned short ushort8;
typedef __attribute__((ext_vector_type(4))) float f32x4;

static __device__ __forceinline__ unsigned short f2bf(float f) {
    union { float f; unsigned int u; } v; v.f = f;
    unsigned int u = v.u;
    return (unsigned short)((u + 0x7FFFu + ((u >> 16) & 1u)) >> 16);
}
static __device__ __forceinline__ float bf2f(unsigned short h) {
    union { unsigned int u; float f; } v; v.u = ((unsigned int)h) << 16;
    return v.f;
}

// async global -> LDS, 16B per lane, dest must be wave-uniform base + lane*16
#define GLOAD16(gsrc, ldst)                                                        \
    __builtin_amdgcn_global_load_lds(                                              \
        (const __attribute__((address_space(1))) void*)(gsrc),                     \
        (__attribute__((address_space(3))) void*)(ldst), 16, 0, 0)

// ---------- prep: 3 weight transposes (fp32->bf16, (R,C)->(C,R)) + router, one launch ----------
// blocks [0,8192): w1 ; [8192,16384): w3 ; [16384,24576): w2 ; [24576,25600): router
__global__ void prep_kernel(const float* __restrict__ w1, const float* __restrict__ w3,
                            const float* __restrict__ w2,
                            unsigned short* __restrict__ w1T, unsigned short* __restrict__ w3T,
                            unsigned short* __restrict__ w2T,
                            const float* __restrict__ x, const float* __restrict__ wr,
                            unsigned short* __restrict__ xb,
                            int* __restrict__ topi, float* __restrict__ topw,
                            float* __restrict__ probsum) {
    __shared__ float tile[64][65];
    const int b = blockIdx.x;
    const int tid = threadIdx.x;
    if (b < 24576) {
        const float* in; unsigned short* out; int R, C, cx, ry;
        const int bb = b & 8191;
        const int e = bb >> 10;
        if (b < 8192)       { in = w1; out = w1T; R = DM; C = DF; cx = bb & 63; ry = (bb >> 6) & 15; }
        else if (b < 16384) { in = w3; out = w3T; R = DM; C = DF; cx = bb & 63; ry = (bb >> 6) & 15; }
        else                { in = w2; out = w2T; R = DF; C = DM; cx = bb & 15; ry = (bb >> 4) & 63; }
        const float* src = in + (size_t)e * R * C;
        unsigned short* dst = out + (size_t)e * R * C;
        const int c0 = cx * 64, r0 = ry * 64;
        #pragma unroll
        for (int i = 0; i < 4; ++i) {
            int idx = tid + i * 256;
            int rr = idx >> 4, cc = idx & 15;
            float4 v = *(const float4*)(src + (size_t)(r0 + rr) * C + c0 + cc * 4);
            tile[rr][cc * 4 + 0] = v.x;
            tile[rr][cc * 4 + 1] = v.y;
            tile[rr][cc * 4 + 2] = v.z;
            tile[rr][cc * 4 + 3] = v.w;
        }
        __syncthreads();
        #pragma unroll
        for (int i = 0; i < 2; ++i) {
            int idx = tid + i * 256;
            int c = idx >> 3, rc = idx & 7;
            ushort8 o;
            #pragma unroll
            for (int j = 0; j < 8; ++j) o[j] = f2bf(tile[rc * 8 + j][c]);
            *(ushort8*)(dst + (size_t)(c0 + c) * R + r0 + rc * 8) = o;
        }
        return;
    }
    // ---- router path ----
    float* s_ps = &tile[0][0];
    if (tid < NE) s_ps[tid] = 0.f;
    __syncthreads();
    const int wid = tid >> 6, lane = tid & 63;
    const int t = (b - 24576) * 4 + wid;
    float acc[NE] = {0.f, 0.f, 0.f, 0.f, 0.f, 0.f, 0.f, 0.f};
    const float* xr = x + (size_t)t * DM;
    unsigned short* xbr = xb + (size_t)t * DM;
    for (int it = 0; it < DM / 64; ++it) {
        int d = it * 64 + lane;
        float xv = xr[d];
        xbr[d] = f2bf(xv);
        const float* w = wr + d * NE;
        #pragma unroll
        for (int e = 0; e < NE; ++e) acc[e] = fmaf(xv, w[e], acc[e]);
    }
    #pragma unroll
    for (int e = 0; e < NE; ++e) {
        float v = acc[e];
        #pragma unroll
        for (int off = 32; off; off >>= 1) v += __shfl_xor(v, off);
        acc[e] = v;
    }
    if (lane == 0) {
        float m = acc[0];
        #pragma unroll
        for (int e = 1; e < NE; ++e) m = fmaxf(m, acc[e]);
        float p[NE], s = 0.f;
        #pragma unroll
        for (int e = 0; e < NE; ++e) { p[e] = expf(acc[e] - m); s += p[e]; }
        float inv = 1.f / s;
        #pragma unroll
        for (int e = 0; e < NE; ++e) { p[e] *= inv; atomicAdd(&s_ps[e], p[e]); }
        int i1 = 0; float p1 = p[0];
        #pragma unroll
        for (int e = 1; e < NE; ++e) if (p[e] > p1) { p1 = p[e]; i1 = e; }
        int i2 = -1; float p2 = -1.f;
        #pragma unroll
        for (int e = 0; e < NE; ++e) if (e != i1 && p[e] > p2) { p2 = p[e]; i2 = e; }
        float rs = 1.f / (p1 + p2);
        topi[t * 2] = i1; topi[t * 2 + 1] = i2;
        topw[t * 2] = p1 * rs; topw[t * 2 + 1] = p2 * rs;
    }
    __syncthreads();
    if (tid < NE) atomicAdd(&probsum[tid], s_ps[tid]);
}

// ---------- deterministic per-expert token compaction (ballot scan) ----------
__global__ void assign_kernel(const int* __restrict__ topi,
                              int* __restrict__ list, int* __restrict__ slotpos,
                              int* __restrict__ cnt) {
    const int e = blockIdx.x;
    __shared__ int s_wc[4];
    const int tid = threadIdx.x, wid = tid >> 6, lane = tid & 63;
    int running = 0;
    for (int base = 0; base < TT; base += 256) {
        int t = base + tid;
        int hit = 0, slot = 0;
        int a = topi[2 * t], b = topi[2 * t + 1];
        if (a == e) { hit = 1; slot = 0; }
        else if (b == e) { hit = 1; slot = 1; }
        unsigned long long m = __ballot(hit);
        if (lane == 0) s_wc[wid] = __popcll(m);
        __syncthreads();
        int pre = 0, tot = 0;
        #pragma unroll
        for (int q = 0; q < 4; ++q) { int c = s_wc[q]; tot += c; if (q < wid) pre += c; }
        if (hit) {
            int pos = running + pre + __popcll(m & ((1ull << lane) - 1ull));
            list[e * TT + pos] = t;
            slotpos[2 * t + slot] = pos;
        }
        running += tot;
        __syncthreads();
    }
    if (tid == 0) cnt[e] = running;
}

// ---------- offsets prefix + aux loss + block tables ----------
__global__ void finalize_kernel(const int* __restrict__ cnt,
                                const float* __restrict__ probsum,
                                int* __restrict__ offs,
                                unsigned int* __restrict__ blocktab,
                                unsigned int* __restrict__ blocktab2,
                                float* __restrict__ out_aux) {
    int o = 0;
    float aux = 0.f;
    int nb = 0, nb2 = 0;
    for (int e = 0; e < NE; ++e) {
        offs[e] = o; o += cnt[e];
        aux += (float)cnt[e] * probsum[e];
        int nrb = (cnt[e] + 127) >> 7;
        for (int rb = 0; rb < nrb; ++rb) blocktab[nb++] = ((unsigned)e << 16) | rb;
        int nrb2 = (cnt[e] + 255) >> 8;
        for (int rb = 0; rb < nrb2; ++rb) blocktab2[nb2++] = ((unsigned)e << 16) | rb;
    }
    while (nb < BTAB) blocktab[nb++] = 0xFFFFFFFFu;
    while (nb2 < BTAB2) blocktab2[nb2++] = 0xFFFFFFFFu;
    *out_aux = (float)NE * aux / ((float)TT * (float)TT);
}

// ==================== GEMM1: 256x128, 2 barriers/K-tile, counted vmcnt ====================
__global__ __launch_bounds__(512, 1) void gemm1_kernel(
    const unsigned short* __restrict__ xb,
    const unsigned short* __restrict__ w1T,
    const unsigned short* __restrict__ w3T,
    unsigned short* __restrict__ act,
    const int* __restrict__ list,
    const int* __restrict__ cnt,
    const int* __restrict__ offs,
    const unsigned int* __restrict__ blocktab2) {
    const int lin = blockIdx.y * 32 + blockIdx.x;      // gridDim.x == 32
    const int xcd = lin & 7, j = lin >> 3;
    const int fcolb = xcd * 4 + (j & 3);
    const int slot = j >> 2;
    const unsigned int tab = blocktab2[slot];
    if (tab == 0xFFFFFFFFu) return;
    const int e = tab >> 16;
    const int rowbase = (int)(tab & 0xFFFFu) << 8;
    const int ce = cnt[e];
    const int fbase = fcolb * 128;

    __shared__ __align__(16) unsigned short lds[65536];   // 128 KiB
    char* ldsC = (char*)lds;

    const int tid = threadIdx.x;                 // 0..511
    const int lane = tid & 63, wid = tid >> 6;
    const int wm = wid >> 2, wn = wid & 3;       // 2M x 4N waves

    const unsigned short* aP[2][2];
    const unsigned short* bP[2][2];
    #pragma unroll
    for (int ci = 0; ci < 2; ++ci) {
        const int c = tid + ci * 512;
        const int r = (c >> 2) & 15, rg = c >> 7, cc = c & 3, ks = (c >> 6) & 1;
        const int row = rg * 16 + r;
        const int kb = ks * 64 + ((cc * 16) ^ ((r & 8) << 2));
        #pragma unroll
        for (int h = 0; h < 2; ++h) {
            int sp = rowbase + h * 128 + row; if (sp >= ce) sp = ce - 1;
            aP[h][ci] = xb + (size_t)list[e * TT + sp] * DM + (kb >> 1);
            const int n = h * 128 + row;
            const int col = fbase + (n >> 5) * 16 + (n & 15);
            const unsigned short* wsrc = ((n >> 4) & 1) ? w3T : w1T;
            bP[h][ci] = wsrc + ((size_t)e * DF + col) * DM + (kb >> 1);
        }
    }

#define STG_A(H, T, B) {                                                          \
    GLOAD16(aP[H][0] + (size_t)(T) * 64, ldsC + (B) * 65536 + (H) * 16384 + tid * 16);        \
    GLOAD16(aP[H][1] + (size_t)(T) * 64, ldsC + (B) * 65536 + (H) * 16384 + 8192 + tid * 16); }
#define STG_B(H, T, B) {                                                          \
    GLOAD16(bP[H][0] + (size_t)(T) * 64, ldsC + (B) * 65536 + 32768 + (H) * 16384 + tid * 16);        \
    GLOAD16(bP[H][1] + (size_t)(T) * 64, ldsC + (B) * 65536 + 32768 + (H) * 16384 + 8192 + tid * 16); }

    const int lofs = ((lane & 15) << 6) + ((((lane >> 4) << 4) ^ ((lane & 8) << 2)));

#define RDA(BB, MQ) { _Pragma("unroll") for (int i = 0; i < 4; ++i) {             \
    _Pragma("unroll") for (int k2 = 0; k2 < 2; ++k2)                              \
        aq[i][k2] = *(const bf16x8*)(ldsC + (BB) + wm * 16384 +                   \
                     (((MQ) * 4 + i) * 2 + k2) * 1024 + lofs); } }
#define RDB(DST, BB, NQ) { _Pragma("unroll") for (int u = 0; u < 2; ++u) {        \
    _Pragma("unroll") for (int k2 = 0; k2 < 2; ++k2)                              \
        DST[u][k2] = *(const bf16x8*)(ldsC + (BB) + 32768 + (wn >> 1) * 16384 +   \
                     (wn & 1) * 8192 + ((NQ) * 2 + u) * 2048 + k2 * 1024 + lofs); } }
#define MMQ(MQ, NQ, BQ) { __builtin_amdgcn_s_setprio(1);                          \
    _Pragma("unroll") for (int i = 0; i < 4; ++i)                                 \
    _Pragma("unroll") for (int u = 0; u < 2; ++u)                                 \
    _Pragma("unroll") for (int k2 = 0; k2 < 2; ++k2)                              \
        acc[(MQ) * 4 + i][(NQ) * 2 + u] = __builtin_amdgcn_mfma_f32_16x16x32_bf16(\
            aq[i][k2], BQ[u][k2], acc[(MQ) * 4 + i][(NQ) * 2 + u], 0, 0, 0);      \
    __builtin_amdgcn_s_setprio(0); }

    f32x4 acc[8][4] = {};
    bf16x8 aq[4][2], b0[2][2], b1[2][2];

    STG_A(0, 0, 0); STG_A(1, 0, 0); STG_B(0, 0, 0); STG_B(1, 0, 0);
    STG_B(0, 1, 1); STG_B(1, 1, 1); STG_A(0, 1, 1);
    asm volatile("s_waitcnt vmcnt(6)" ::: "memory");
    __builtin_amdgcn_s_barrier();

    #pragma unroll 1
    for (int h = 0; h < 16; ++h) {
        const int bb = (h & 1) * 65536;
        // reads of cur buf + quadrant MFMAs; stage A-h1(t+1) -> other buf early
        RDA(bb, 0) RDB(b0, bb, 0)
        if (h < 15) STG_A(1, h + 1, (h & 1) ^ 1);
        MMQ(0, 0, b0)
        RDB(b1, bb, 1)
        MMQ(0, 1, b1)
        RDA(bb, 1)
        MMQ(1, 0, b0)
        // all ds_reads of cur buf consumed by MFMAs above -> safe to overwrite after barrier
        __builtin_amdgcn_s_barrier();
        if (h < 14) { STG_B(0, h + 2, h & 1); STG_B(1, h + 2, h & 1); STG_A(0, h + 2, h & 1); }
        MMQ(1, 1, b1)
        if (h < 14)       { asm volatile("s_waitcnt vmcnt(6)" ::: "memory"); }
        else if (h == 14) { asm volatile("s_waitcnt vmcnt(0)" ::: "memory"); }
        __builtin_amdgcn_s_barrier();
    }
#undef STG_A
#undef STG_B
#undef RDA
#undef RDB
#undef MMQ

    const int ob = offs[e];
    const int g = lane >> 4, rr = lane & 15;
    #pragma unroll
    for (int m = 0; m < 8; ++m) {
        #pragma unroll
        for (int j2 = 0; j2 < 4; ++j2) {
            const int pos = rowbase + wm * 128 + m * 16 + g * 4 + j2;
            if (pos < ce) {
                unsigned short* arow = act + (size_t)(ob + pos) * DF + fbase + wn * 32;
                #pragma unroll
                for (int p = 0; p < 2; ++p) {
                    float hv = acc[m][2 * p][j2];
                    float gv = acc[m][2 * p + 1][j2];
                    float a = (hv / (1.f + __expf(-hv))) * gv;
                    arow[p * 16 + rr] = f2bf(a);
                }
            }
        }
    }
}

// ==================== GEMM2: 128x128, BK=64, dbuf 64KB, 2 blocks/CU (R9) ====================
__global__ __launch_bounds__(256, 2) void gemm2_kernel(
    const unsigned short* __restrict__ act,
    const unsigned short* __restrict__ w2T,
    unsigned short* __restrict__ ybuf,
    const int* __restrict__ cnt,
    const int* __restrict__ offs,
    const unsigned int* __restrict__ blocktab) {
    const unsigned int tab = blocktab[blockIdx.y];
    if (tab == 0xFFFFFFFFu) return;
    const int e = tab >> 16;
    const int rowbase = (int)(tab & 0xFFFFu) << 7;
    const int ce = cnt[e];
    const int ob = offs[e];
    const int dbase = blockIdx.x * 128;          // gridDim.x == 8

    __shared__ __align__(16) unsigned short lds[32768];   // 64 KiB
    char* ldsC = (char*)lds;

    const int tid = threadIdx.x;                 // 0..255
    const int lane = tid & 63, wid = tid >> 6;
    const int wm = wid >> 1, wn = wid & 1;       // 2M x 2N waves, wave tile 64x64

    const unsigned short* aP[4];
    const unsigned short* bP[4];
    #pragma unroll
    for (int ci = 0; ci < 4; ++ci) {
        const int c = tid + ci * 256;                      // 0..1023
        const int rg = c >> 7, ks = (c >> 6) & 1, r = (c >> 2) & 15, cc = c & 3;
        const int row = rg * 16 + r;                       // 0..127
        const int kb = ks * 64 + ((cc * 16) ^ ((r & 8) << 2));
        int sp = rowbase + row; if (sp >= ce) sp = ce - 1;
        aP[ci] = act + (size_t)(ob + sp) * DF + (kb >> 1);
        bP[ci] = w2T + ((size_t)e * DM + dbase + row) * DF + (kb >> 1);
    }

#define STG2(T, B) { _Pragma("unroll") for (int ci = 0; ci < 4; ++ci) {           \
        GLOAD16(aP[ci] + (size_t)(T) * 64, ldsC + (B) * 32768 + ci * 4096 + tid * 16);         \
        GLOAD16(bP[ci] + (size_t)(T) * 64, ldsC + (B) * 32768 + 16384 + ci * 4096 + tid * 16); } }

    const int lofs = ((lane & 15) << 6) + ((((lane >> 4) << 4) ^ ((lane & 8) << 2)));

    f32x4 acc[4][4] = {};

    const int NT = DF / 64;   // 64 K-tiles
    STG2(0, 0)
    asm volatile("s_waitcnt vmcnt(0)" ::: "memory");
    __builtin_amdgcn_s_barrier();

    #pragma unroll 2
    for (int h = 0; h < NT; ++h) {
        const int bb = (h & 1) * 32768;
        if (h + 1 < NT) STG2(h + 1, (h & 1) ^ 1)
        bf16x8 aq[4][2], bq[4][2];
        #pragma unroll
        for (int m = 0; m < 4; ++m)
            #pragma unroll
            for (int k2 = 0; k2 < 2; ++k2)
                aq[m][k2] = *(const bf16x8*)(ldsC + bb + (wm * 4 + m) * 2048 + k2 * 1024 + lofs);
        #pragma unroll
        for (int u = 0; u < 4; ++u)
            #pragma unroll
            for (int k2 = 0; k2 < 2; ++k2)
                bq[u][k2] = *(const bf16x8*)(ldsC + bb + 16384 + (wn * 4 + u) * 2048 + k2 * 1024 + lofs);
        __builtin_amdgcn_sched_barrier(0);
        __builtin_amdgcn_s_setprio(1);
        #pragma unroll
        for (int k2 = 0; k2 < 2; ++k2)
            #pragma unroll
            for (int u = 0; u < 4; ++u)
                #pragma unroll
                for (int m = 0; m < 4; ++m)
                    acc[m][u] = __builtin_amdgcn_mfma_f32_16x16x32_bf16(aq[m][k2], bq[u][k2], acc[m][u], 0, 0, 0);
        __builtin_amdgcn_s_setprio(0);
        if (h + 1 < NT) {
            asm volatile("s_waitcnt vmcnt(0)" ::: "memory");
            __builtin_amdgcn_s_barrier();
        }
    }
#undef STG2

    const int g = lane >> 4, rr = lane & 15;
    #pragma unroll
    for (int m = 0; m < 4; ++m) {
        #pragma unroll
        for (int j2 = 0; j2 < 4; ++j2) {
            const int pos = rowbase + wm * 64 + m * 16 + g * 4 + j2;
            if (pos < ce) {
                unsigned short* yrow = ybuf + (size_t)(ob + pos) * DM + dbase + wn * 64;
                #pragma unroll
                for (int u = 0; u < 4; ++u)
                    yrow[u * 16 + rr] = f2bf(acc[m][u][j2]);
            }
        }
    }
}

// ---------- combine: out[t] = w0*ybuf[row0] + w1*ybuf[row1] ----------
__global__ void combine_kernel(const unsigned short* __restrict__ ybuf,
                               const int* __restrict__ topi,
                               const float* __restrict__ topw,
                               const int* __restrict__ slotpos,
                               const int* __restrict__ offs,
                               float* __restrict__ out) {
    const int t = blockIdx.x;
    const int tid = threadIdx.x;
    const int e0 = topi[2 * t], e1 = topi[2 * t + 1];
    const int r0 = offs[e0] + slotpos[2 * t];
    const int r1 = offs[e1] + slotpos[2 * t + 1];
    const float w0 = topw[2 * t], w1 = topw[2 * t + 1];
    ushort4 a = *(const ushort4*)(ybuf + (size_t)r0 * DM + tid * 4);
    ushort4 b = *(const ushort4*)(ybuf + (size_t)r1 * DM + tid * 4);
    float4 o;
    o.x = w0 * bf2f(a.x) + w1 * bf2f(b.x);
    o.y = w0 * bf2f(a.y) + w1 * bf2f(b.y);
    o.z = w0 * bf2f(a.z) + w1 * bf2f(b.z);
    o.w = w0 * bf2f(a.w) + w1 * bf2f(b.w);
    *(float4*)(out + (size_t)t * DM + tid * 4) = o;
}

extern "C" void kernel_launch(void* const* d_in, const int* in_sizes, int n_in,
                              void* d_out, int out_size, void* d_ws, size_t ws_size,
                              hipStream_t stream) {
    (void)in_sizes; (void)n_in; (void)ws_size;
    const float* x  = (const float*)d_in[0];
    const float* wr = (const float*)d_in[1];
    const float* w1 = (const float*)d_in[2];
    const float* w2 = (const float*)d_in[3];
    const float* w3 = (const float*)d_in[4];
    float* out = (float*)d_out;

    char* ws = (char*)d_ws;
    size_t off = 0;
    auto alloc = [&](size_t bytes) -> void* {
        void* p = ws + off;
        off = (off + bytes + 255) & ~(size_t)255;
        return p;
    };
    unsigned short* w1T = (unsigned short*)alloc((size_t)NE * DF * DM * 2);
    unsigned short* w3T = (unsigned short*)alloc((size_t)NE * DF * DM * 2);
    unsigned short* w2T = (unsigned short*)alloc((size_t)NE * DM * DF * 2);
    unsigned short* act = (unsigned short*)alloc((size_t)2 * TT * DF * 2);
    unsigned short* xb  = (unsigned short*)alloc((size_t)TT * DM * 2);
    int*   topi    = (int*)alloc(TT * 2 * sizeof(int));
    float* topw    = (float*)alloc(TT * 2 * sizeof(float));
    int*   list    = (int*)alloc((size_t)NE * TT * sizeof(int));
    int*   slotpos = (int*)alloc(TT * 2 * sizeof(int));
    int*   cnt     = (int*)alloc(NE * sizeof(int));
    int*   offs    = (int*)alloc(NE * sizeof(int));
    float* probsum = (float*)alloc(NE * sizeof(float));
    unsigned int* blocktab  = (unsigned int*)alloc(BTAB * sizeof(unsigned int));
    unsigned int* blocktab2 = (unsigned int*)alloc(BTAB2 * sizeof(unsigned int));
    // ybuf (2*TT x DM bf16 = 16.8 MB) aliases w1T (dead after gemm1)
    unsigned short* ybuf = w1T;

    hipMemsetAsync(probsum, 0, NE * sizeof(float), stream);

    prep_kernel<<<25600, 256, 0, stream>>>(w1, w3, w2, w1T, w3T, w2T,
                                           x, wr, xb, topi, topw, probsum);
    assign_kernel<<<NE, 256, 0, stream>>>(topi, list, slotpos, cnt);
    finalize_kernel<<<1, 1, 0, stream>>>(cnt, probsum, offs, blocktab, blocktab2, out + (out_size - 1));

    gemm1_kernel<<<dim3(32, BTAB2), 512, 0, stream>>>(xb, w1T, w3T, act, list, cnt, offs, blocktab2);
    gemm2_kernel<<<dim3(8, BTAB), 256, 0, stream>>>(act, w2T, ybuf, cnt, offs, blocktab);
    combine_kernel<<<TT, 256, 0, stream>>>(ybuf, topi, topw, slotpos, offs, out);
}

// Round 15
// 422.462 us; speedup vs baseline: 1.0024x; 1.0024x over previous
//
#include <hip/hip_runtime.h>
#include <hip/hip_bf16.h>
#include <cstdint>
#include <cstddef>

#define TT 4096   // tokens
#define DM 1024   // d_model
#define DF 4096   // d_ffn
#define NE 8      // experts
#define BTAB 72   // max 128-row blocks over all experts
#define BTAB2 40  // max 256-row blocks over all experts

typedef __attribute__((ext_vector_type(8))) short bf16x8;
typedef __attribute__((ext_vector_type(8))) unsigned short ushort8;
typedef __attribute__((ext_vector_type(4))) float f32x4;

static __device__ __forceinline__ unsigned short f2bf(float f) {
    union { float f; unsigned int u; } v; v.f = f;
    unsigned int u = v.u;
    return (unsigned short)((u + 0x7FFFu + ((u >> 16) & 1u)) >> 16);
}
static __device__ __forceinline__ float bf2f(unsigned short h) {
    union { unsigned int u; float f; } v; v.u = ((unsigned int)h) << 16;
    return v.f;
}

// async global -> LDS, 16B per lane, dest must be wave-uniform base + lane*16
#define GLOAD16(gsrc, ldst)                                                        \
    __builtin_amdgcn_global_load_lds(                                              \
        (const __attribute__((address_space(1))) void*)(gsrc),                     \
        (__attribute__((address_space(3))) void*)(ldst), 16, 0, 0)

// ---------- prep: 3 weight transposes (fp32->bf16, (R,C)->(C,R)) + router, one launch ----------
// blocks [0,8192): w1 ; [8192,16384): w3 ; [16384,24576): w2 ; [24576,25600): router
__global__ void prep_kernel(const float* __restrict__ w1, const float* __restrict__ w3,
                            const float* __restrict__ w2,
                            unsigned short* __restrict__ w1T, unsigned short* __restrict__ w3T,
                            unsigned short* __restrict__ w2T,
                            const float* __restrict__ x, const float* __restrict__ wr,
                            unsigned short* __restrict__ xb,
                            int* __restrict__ topi, float* __restrict__ topw,
                            float* __restrict__ probsum) {
    __shared__ float tile[64][65];
    const int b = blockIdx.x;
    const int tid = threadIdx.x;
    if (b < 24576) {
        const float* in; unsigned short* out; int R, C, cx, ry;
        const int bb = b & 8191;
        const int e = bb >> 10;
        if (b < 8192)       { in = w1; out = w1T; R = DM; C = DF; cx = bb & 63; ry = (bb >> 6) & 15; }
        else if (b < 16384) { in = w3; out = w3T; R = DM; C = DF; cx = bb & 63; ry = (bb >> 6) & 15; }
        else                { in = w2; out = w2T; R = DF; C = DM; cx = bb & 15; ry = (bb >> 4) & 63; }
        const float* src = in + (size_t)e * R * C;
        unsigned short* dst = out + (size_t)e * R * C;
        const int c0 = cx * 64, r0 = ry * 64;
        #pragma unroll
        for (int i = 0; i < 4; ++i) {
            int idx = tid + i * 256;
            int rr = idx >> 4, cc = idx & 15;
            float4 v = *(const float4*)(src + (size_t)(r0 + rr) * C + c0 + cc * 4);
            tile[rr][cc * 4 + 0] = v.x;
            tile[rr][cc * 4 + 1] = v.y;
            tile[rr][cc * 4 + 2] = v.z;
            tile[rr][cc * 4 + 3] = v.w;
        }
        __syncthreads();
        #pragma unroll
        for (int i = 0; i < 2; ++i) {
            int idx = tid + i * 256;
            int c = idx >> 3, rc = idx & 7;
            ushort8 o;
            #pragma unroll
            for (int j = 0; j < 8; ++j) o[j] = f2bf(tile[rc * 8 + j][c]);
            *(ushort8*)(dst + (size_t)(c0 + c) * R + r0 + rc * 8) = o;
        }
        return;
    }
    // ---- router path ----
    float* s_ps = &tile[0][0];
    if (tid < NE) s_ps[tid] = 0.f;
    __syncthreads();
    const int wid = tid >> 6, lane = tid & 63;
    const int t = (b - 24576) * 4 + wid;
    float acc[NE] = {0.f, 0.f, 0.f, 0.f, 0.f, 0.f, 0.f, 0.f};
    const float* xr = x + (size_t)t * DM;
    unsigned short* xbr = xb + (size_t)t * DM;
    for (int it = 0; it < DM / 64; ++it) {
        int d = it * 64 + lane;
        float xv = xr[d];
        xbr[d] = f2bf(xv);
        const float* w = wr + d * NE;
        #pragma unroll
        for (int e = 0; e < NE; ++e) acc[e] = fmaf(xv, w[e], acc[e]);
    }
    #pragma unroll
    for (int e = 0; e < NE; ++e) {
        float v = acc[e];
        #pragma unroll
        for (int off = 32; off; off >>= 1) v += __shfl_xor(v, off);
        acc[e] = v;
    }
    if (lane == 0) {
        float m = acc[0];
        #pragma unroll
        for (int e = 1; e < NE; ++e) m = fmaxf(m, acc[e]);
        float p[NE], s = 0.f;
        #pragma unroll
        for (int e = 0; e < NE; ++e) { p[e] = expf(acc[e] - m); s += p[e]; }
        float inv = 1.f / s;
        #pragma unroll
        for (int e = 0; e < NE; ++e) { p[e] *= inv; atomicAdd(&s_ps[e], p[e]); }
        int i1 = 0; float p1 = p[0];
        #pragma unroll
        for (int e = 1; e < NE; ++e) if (p[e] > p1) { p1 = p[e]; i1 = e; }
        int i2 = -1; float p2 = -1.f;
        #pragma unroll
        for (int e = 0; e < NE; ++e) if (e != i1 && p[e] > p2) { p2 = p[e]; i2 = e; }
        float rs = 1.f / (p1 + p2);
        topi[t * 2] = i1; topi[t * 2 + 1] = i2;
        topw[t * 2] = p1 * rs; topw[t * 2 + 1] = p2 * rs;
    }
    __syncthreads();
    if (tid < NE) atomicAdd(&probsum[tid], s_ps[tid]);
}

// ---------- deterministic per-expert token compaction (ballot scan) ----------
__global__ void assign_kernel(const int* __restrict__ topi,
                              int* __restrict__ list, int* __restrict__ slotpos,
                              int* __restrict__ cnt) {
    const int e = blockIdx.x;
    __shared__ int s_wc[4];
    const int tid = threadIdx.x, wid = tid >> 6, lane = tid & 63;
    int running = 0;
    for (int base = 0; base < TT; base += 256) {
        int t = base + tid;
        int hit = 0, slot = 0;
        int a = topi[2 * t], b = topi[2 * t + 1];
        if (a == e) { hit = 1; slot = 0; }
        else if (b == e) { hit = 1; slot = 1; }
        unsigned long long m = __ballot(hit);
        if (lane == 0) s_wc[wid] = __popcll(m);
        __syncthreads();
        int pre = 0, tot = 0;
        #pragma unroll
        for (int q = 0; q < 4; ++q) { int c = s_wc[q]; tot += c; if (q < wid) pre += c; }
        if (hit) {
            int pos = running + pre + __popcll(m & ((1ull << lane) - 1ull));
            list[e * TT + pos] = t;
            slotpos[2 * t + slot] = pos;
        }
        running += tot;
        __syncthreads();
    }
    if (tid == 0) cnt[e] = running;
}

// ---------- offsets prefix + aux loss + block tables ----------
__global__ void finalize_kernel(const int* __restrict__ cnt,
                                const float* __restrict__ probsum,
                                int* __restrict__ offs,
                                unsigned int* __restrict__ blocktab,
                                unsigned int* __restrict__ blocktab2,
                                float* __restrict__ out_aux) {
    int o = 0;
    float aux = 0.f;
    int nb = 0, nb2 = 0;
    for (int e = 0; e < NE; ++e) {
        offs[e] = o; o += cnt[e];
        aux += (float)cnt[e] * probsum[e];
        int nrb = (cnt[e] + 127) >> 7;
        for (int rb = 0; rb < nrb; ++rb) blocktab[nb++] = ((unsigned)e << 16) | rb;
        int nrb2 = (cnt[e] + 255) >> 8;
        for (int rb = 0; rb < nrb2; ++rb) blocktab2[nb2++] = ((unsigned)e << 16) | rb;
    }
    while (nb < BTAB) blocktab[nb++] = 0xFFFFFFFFu;
    while (nb2 < BTAB2) blocktab2[nb2++] = 0xFFFFFFFFu;
    *out_aux = (float)NE * aux / ((float)TT * (float)TT);
}

// ==================== GEMM1: 256x128, 2 barriers/K-tile, counted vmcnt ====================
__global__ __launch_bounds__(512, 1) void gemm1_kernel(
    const unsigned short* __restrict__ xb,
    const unsigned short* __restrict__ w1T,
    const unsigned short* __restrict__ w3T,
    unsigned short* __restrict__ act,
    const int* __restrict__ list,
    const int* __restrict__ cnt,
    const int* __restrict__ offs,
    const unsigned int* __restrict__ blocktab2) {
    const int lin = blockIdx.y * 32 + blockIdx.x;      // gridDim.x == 32
    const int xcd = lin & 7, j = lin >> 3;
    const int fcolb = xcd * 4 + (j & 3);
    const int slot = j >> 2;
    const unsigned int tab = blocktab2[slot];
    if (tab == 0xFFFFFFFFu) return;
    const int e = tab >> 16;
    const int rowbase = (int)(tab & 0xFFFFu) << 8;
    const int ce = cnt[e];
    const int fbase = fcolb * 128;

    __shared__ __align__(16) unsigned short lds[65536];   // 128 KiB
    char* ldsC = (char*)lds;

    const int tid = threadIdx.x;                 // 0..511
    const int lane = tid & 63, wid = tid >> 6;
    const int wm = wid >> 2, wn = wid & 3;       // 2M x 4N waves

    const unsigned short* aP[2][2];
    const unsigned short* bP[2][2];
    #pragma unroll
    for (int ci = 0; ci < 2; ++ci) {
        const int c = tid + ci * 512;
        const int r = (c >> 2) & 15, rg = c >> 7, cc = c & 3, ks = (c >> 6) & 1;
        const int row = rg * 16 + r;
        const int kb = ks * 64 + ((cc * 16) ^ ((r & 8) << 2));
        #pragma unroll
        for (int h = 0; h < 2; ++h) {
            int sp = rowbase + h * 128 + row; if (sp >= ce) sp = ce - 1;
            aP[h][ci] = xb + (size_t)list[e * TT + sp] * DM + (kb >> 1);
            const int n = h * 128 + row;
            const int col = fbase + (n >> 5) * 16 + (n & 15);
            const unsigned short* wsrc = ((n >> 4) & 1) ? w3T : w1T;
            bP[h][ci] = wsrc + ((size_t)e * DF + col) * DM + (kb >> 1);
        }
    }

#define STG_A(H, T, B) {                                                          \
    GLOAD16(aP[H][0] + (size_t)(T) * 64, ldsC + (B) * 65536 + (H) * 16384 + tid * 16);        \
    GLOAD16(aP[H][1] + (size_t)(T) * 64, ldsC + (B) * 65536 + (H) * 16384 + 8192 + tid * 16); }
#define STG_B(H, T, B) {                                                          \
    GLOAD16(bP[H][0] + (size_t)(T) * 64, ldsC + (B) * 65536 + 32768 + (H) * 16384 + tid * 16);        \
    GLOAD16(bP[H][1] + (size_t)(T) * 64, ldsC + (B) * 65536 + 32768 + (H) * 16384 + 8192 + tid * 16); }

    const int lofs = ((lane & 15) << 6) + ((((lane >> 4) << 4) ^ ((lane & 8) << 2)));

#define RDA(BB, MQ) { _Pragma("unroll") for (int i = 0; i < 4; ++i) {             \
    _Pragma("unroll") for (int k2 = 0; k2 < 2; ++k2)                              \
        aq[i][k2] = *(const bf16x8*)(ldsC + (BB) + wm * 16384 +                   \
                     (((MQ) * 4 + i) * 2 + k2) * 1024 + lofs); } }
#define RDB(DST, BB, NQ) { _Pragma("unroll") for (int u = 0; u < 2; ++u) {        \
    _Pragma("unroll") for (int k2 = 0; k2 < 2; ++k2)                              \
        DST[u][k2] = *(const bf16x8*)(ldsC + (BB) + 32768 + (wn >> 1) * 16384 +   \
                     (wn & 1) * 8192 + ((NQ) * 2 + u) * 2048 + k2 * 1024 + lofs); } }
#define MMQ(MQ, NQ, BQ) { __builtin_amdgcn_s_setprio(1);                          \
    _Pragma("unroll") for (int i = 0; i < 4; ++i)                                 \
    _Pragma("unroll") for (int u = 0; u < 2; ++u)                                 \
    _Pragma("unroll") for (int k2 = 0; k2 < 2; ++k2)                              \
        acc[(MQ) * 4 + i][(NQ) * 2 + u] = __builtin_amdgcn_mfma_f32_16x16x32_bf16(\
            aq[i][k2], BQ[u][k2], acc[(MQ) * 4 + i][(NQ) * 2 + u], 0, 0, 0);      \
    __builtin_amdgcn_s_setprio(0); }

    f32x4 acc[8][4] = {};
    bf16x8 aq[4][2], b0[2][2], b1[2][2];

    STG_A(0, 0, 0); STG_A(1, 0, 0); STG_B(0, 0, 0); STG_B(1, 0, 0);
    STG_B(0, 1, 1); STG_B(1, 1, 1); STG_A(0, 1, 1);
    asm volatile("s_waitcnt vmcnt(6)" ::: "memory");
    __builtin_amdgcn_s_barrier();

    #pragma unroll 1
    for (int h = 0; h < 16; ++h) {
        const int bb = (h & 1) * 65536;
        // reads of cur buf + quadrant MFMAs; stage A-h1(t+1) -> other buf early
        RDA(bb, 0) RDB(b0, bb, 0)
        if (h < 15) STG_A(1, h + 1, (h & 1) ^ 1);
        MMQ(0, 0, b0)
        RDB(b1, bb, 1)
        MMQ(0, 1, b1)
        RDA(bb, 1)
        MMQ(1, 0, b0)
        // all ds_reads of cur buf consumed by MFMAs above -> safe to overwrite after barrier
        __builtin_amdgcn_s_barrier();
        if (h < 14) { STG_B(0, h + 2, h & 1); STG_B(1, h + 2, h & 1); STG_A(0, h + 2, h & 1); }
        MMQ(1, 1, b1)
        if (h < 14)       { asm volatile("s_waitcnt vmcnt(6)" ::: "memory"); }
        else if (h == 14) { asm volatile("s_waitcnt vmcnt(0)" ::: "memory"); }
        __builtin_amdgcn_s_barrier();
    }
#undef STG_A
#undef STG_B
#undef RDA
#undef RDB
#undef MMQ

    const int ob = offs[e];
    const int g = lane >> 4, rr = lane & 15;
    #pragma unroll
    for (int m = 0; m < 8; ++m) {
        #pragma unroll
        for (int j2 = 0; j2 < 4; ++j2) {
            const int pos = rowbase + wm * 128 + m * 16 + g * 4 + j2;
            if (pos < ce) {
                unsigned short* arow = act + (size_t)(ob + pos) * DF + fbase + wn * 32;
                #pragma unroll
                for (int p = 0; p < 2; ++p) {
                    float hv = acc[m][2 * p][j2];
                    float gv = acc[m][2 * p + 1][j2];
                    float a = (hv / (1.f + __expf(-hv))) * gv;
                    arow[p * 16 + rr] = f2bf(a);
                }
            }
        }
    }
}

// ==================== GEMM2: 128x128, BK=64, dbuf 64KB, 2 blocks/CU (R9) ====================
__global__ __launch_bounds__(256, 2) void gemm2_kernel(
    const unsigned short* __restrict__ act,
    const unsigned short* __restrict__ w2T,
    unsigned short* __restrict__ ybuf,
    const int* __restrict__ cnt,
    const int* __restrict__ offs,
    const unsigned int* __restrict__ blocktab) {
    const unsigned int tab = blocktab[blockIdx.y];
    if (tab == 0xFFFFFFFFu) return;
    const int e = tab >> 16;
    const int rowbase = (int)(tab & 0xFFFFu) << 7;
    const int ce = cnt[e];
    const int ob = offs[e];
    const int dbase = blockIdx.x * 128;          // gridDim.x == 8

    __shared__ __align__(16) unsigned short lds[32768];   // 64 KiB
    char* ldsC = (char*)lds;

    const int tid = threadIdx.x;                 // 0..255
    const int lane = tid & 63, wid = tid >> 6;
    const int wm = wid >> 1, wn = wid & 1;       // 2M x 2N waves, wave tile 64x64

    const unsigned short* aP[4];
    const unsigned short* bP[4];
    #pragma unroll
    for (int ci = 0; ci < 4; ++ci) {
        const int c = tid + ci * 256;                      // 0..1023
        const int rg = c >> 7, ks = (c >> 6) & 1, r = (c >> 2) & 15, cc = c & 3;
        const int row = rg * 16 + r;                       // 0..127
        const int kb = ks * 64 + ((cc * 16) ^ ((r & 8) << 2));
        int sp = rowbase + row; if (sp >= ce) sp = ce - 1;
        aP[ci] = act + (size_t)(ob + sp) * DF + (kb >> 1);
        bP[ci] = w2T + ((size_t)e * DM + dbase + row) * DF + (kb >> 1);
    }

#define STG2(T, B) { _Pragma("unroll") for (int ci = 0; ci < 4; ++ci) {           \
        GLOAD16(aP[ci] + (size_t)(T) * 64, ldsC + (B) * 32768 + ci * 4096 + tid * 16);         \
        GLOAD16(bP[ci] + (size_t)(T) * 64, ldsC + (B) * 32768 + 16384 + ci * 4096 + tid * 16); } }

    const int lofs = ((lane & 15) << 6) + ((((lane >> 4) << 4) ^ ((lane & 8) << 2)));

    f32x4 acc[4][4] = {};

    const int NT = DF / 64;   // 64 K-tiles
    STG2(0, 0)
    asm volatile("s_waitcnt vmcnt(0)" ::: "memory");
    __builtin_amdgcn_s_barrier();

    #pragma unroll 2
    for (int h = 0; h < NT; ++h) {
        const int bb = (h & 1) * 32768;
        if (h + 1 < NT) STG2(h + 1, (h & 1) ^ 1)
        bf16x8 aq[4][2], bq[4][2];
        #pragma unroll
        for (int m = 0; m < 4; ++m)
            #pragma unroll
            for (int k2 = 0; k2 < 2; ++k2)
                aq[m][k2] = *(const bf16x8*)(ldsC + bb + (wm * 4 + m) * 2048 + k2 * 1024 + lofs);
        #pragma unroll
        for (int u = 0; u < 4; ++u)
            #pragma unroll
            for (int k2 = 0; k2 < 2; ++k2)
                bq[u][k2] = *(const bf16x8*)(ldsC + bb + 16384 + (wn * 4 + u) * 2048 + k2 * 1024 + lofs);
        __builtin_amdgcn_sched_barrier(0);
        __builtin_amdgcn_s_setprio(1);
        #pragma unroll
        for (int k2 = 0; k2 < 2; ++k2)
            #pragma unroll
            for (int u = 0; u < 4; ++u)
                #pragma unroll
                for (int m = 0; m < 4; ++m)
                    acc[m][u] = __builtin_amdgcn_mfma_f32_16x16x32_bf16(aq[m][k2], bq[u][k2], acc[m][u], 0, 0, 0);
        __builtin_amdgcn_s_setprio(0);
        if (h + 1 < NT) {
            asm volatile("s_waitcnt vmcnt(0)" ::: "memory");
            __builtin_amdgcn_s_barrier();
        }
    }
#undef STG2

    const int g = lane >> 4, rr = lane & 15;
    #pragma unroll
    for (int m = 0; m < 4; ++m) {
        #pragma unroll
        for (int j2 = 0; j2 < 4; ++j2) {
            const int pos = rowbase + wm * 64 + m * 16 + g * 4 + j2;
            if (pos < ce) {
                unsigned short* yrow = ybuf + (size_t)(ob + pos) * DM + dbase + wn * 64;
                #pragma unroll
                for (int u = 0; u < 4; ++u)
                    yrow[u * 16 + rr] = f2bf(acc[m][u][j2]);
            }
        }
    }
}

// ---------- combine: out[t] = w0*ybuf[row0] + w1*ybuf[row1] ----------
__global__ void combine_kernel(const unsigned short* __restrict__ ybuf,
                               const int* __restrict__ topi,
                               const float* __restrict__ topw,
                               const int* __restrict__ slotpos,
                               const int* __restrict__ offs,
                               float* __restrict__ out) {
    const int t = blockIdx.x;
    const int tid = threadIdx.x;
    const int e0 = topi[2 * t], e1 = topi[2 * t + 1];
    const int r0 = offs[e0] + slotpos[2 * t];
    const int r1 = offs[e1] + slotpos[2 * t + 1];
    const float w0 = topw[2 * t], w1 = topw[2 * t + 1];
    ushort4 a = *(const ushort4*)(ybuf + (size_t)r0 * DM + tid * 4);
    ushort4 b = *(const ushort4*)(ybuf + (size_t)r1 * DM + tid * 4);
    float4 o;
    o.x = w0 * bf2f(a.x) + w1 * bf2f(b.x);
    o.y = w0 * bf2f(a.y) + w1 * bf2f(b.y);
    o.z = w0 * bf2f(a.z) + w1 * bf2f(b.z);
    o.w = w0 * bf2f(a.w) + w1 * bf2f(b.w);
    *(float4*)(out + (size_t)t * DM + tid * 4) = o;
}

extern "C" void kernel_launch(void* const* d_in, const int* in_sizes, int n_in,
                              void* d_out, int out_size, void* d_ws, size_t ws_size,
                              hipStream_t stream) {
    (void)in_sizes; (void)n_in; (void)ws_size;
    const float* x  = (const float*)d_in[0];
    const float* wr = (const float*)d_in[1];
    const float* w1 = (const float*)d_in[2];
    const float* w2 = (const float*)d_in[3];
    const float* w3 = (const float*)d_in[4];
    float* out = (float*)d_out;

    char* ws = (char*)d_ws;
    size_t off = 0;
    auto alloc = [&](size_t bytes) -> void* {
        void* p = ws + off;
        off = (off + bytes + 255) & ~(size_t)255;
        return p;
    };
    unsigned short* w1T = (unsigned short*)alloc((size_t)NE * DF * DM * 2);
    unsigned short* w3T = (unsigned short*)alloc((size_t)NE * DF * DM * 2);
    unsigned short* w2T = (unsigned short*)alloc((size_t)NE * DM * DF * 2);
    unsigned short* act = (unsigned short*)alloc((size_t)2 * TT * DF * 2);
    unsigned short* xb  = (unsigned short*)alloc((size_t)TT * DM * 2);
    int*   topi    = (int*)alloc(TT * 2 * sizeof(int));
    float* topw    = (float*)alloc(TT * 2 * sizeof(float));
    int*   list    = (int*)alloc((size_t)NE * TT * sizeof(int));
    int*   slotpos = (int*)alloc(TT * 2 * sizeof(int));
    int*   cnt     = (int*)alloc(NE * sizeof(int));
    int*   offs    = (int*)alloc(NE * sizeof(int));
    float* probsum = (float*)alloc(NE * sizeof(float));
    unsigned int* blocktab  = (unsigned int*)alloc(BTAB * sizeof(unsigned int));
    unsigned int* blocktab2 = (unsigned int*)alloc(BTAB2 * sizeof(unsigned int));
    // ybuf (2*TT x DM bf16 = 16.8 MB) aliases w1T (dead after gemm1)
    unsigned short* ybuf = w1T;

    hipMemsetAsync(probsum, 0, NE * sizeof(float), stream);

    prep_kernel<<<25600, 256, 0, stream>>>(w1, w3, w2, w1T, w3T, w2T,
                                           x, wr, xb, topi, topw, probsum);
    assign_kernel<<<NE, 256, 0, stream>>>(topi, list, slotpos, cnt);
    finalize_kernel<<<1, 1, 0, stream>>>(cnt, probsum, offs, blocktab, blocktab2, out + (out_size - 1));

    gemm1_kernel<<<dim3(32, BTAB2), 512, 0, stream>>>(xb, w1T, w3T, act, list, cnt, offs, blocktab2);
    gemm2_kernel<<<dim3(8, BTAB), 256, 0, stream>>>(act, w2T, ybuf, cnt, offs, blocktab);
    combine_kernel<<<TT, 256, 0, stream>>>(ybuf, topi, topw, slotpos, offs, out);
}